// Round 17
// baseline (839.014 us; speedup 1.0000x reference)
//
#include <hip/hip_runtime.h>
#include <hip/hip_bf16.h>
#include <math.h>

// Problem constants: V=96, D=128, T=64, H=8, HD=16, FF=512, L=4, B=4096
#define PREP_THR 512

typedef __attribute__((ext_vector_type(8))) short bf16x8;
typedef __attribute__((ext_vector_type(4))) short bf16x4;
typedef __attribute__((ext_vector_type(4))) float f32x4;

#define MFMA32(a, b, c) __builtin_amdgcn_mfma_f32_16x16x32_bf16((a), (b), (c), 0, 0, 0)

#if defined(__has_builtin)
#if __has_builtin(__builtin_amdgcn_mfma_f32_16x16x16bf16_1k)
#define HAVE_MFMA16 1
#endif
#endif
#ifdef HAVE_MFMA16
#define MFMA16(a, b, c) __builtin_amdgcn_mfma_f32_16x16x16bf16_1k((a), (b), (c), 0, 0, 0)
#else
__device__ __forceinline__ f32x4 mfma16_fb(bf16x4 a, bf16x4 b, f32x4 c) {
  asm volatile("s_nop 1\n\tv_mfma_f32_16x16x16_bf16 %0, %1, %2, %0\n\ts_nop 7\n\ts_nop 7"
               : "+v"(c) : "v"(a), "v"(b));
  return c;
}
#define MFMA16(a, b, c) mfma16_fb((a), (b), (c))
#endif

// ---- workspace layout (bf16 element offsets) ----
// Weights bf16, TILE-MAJOR swizzle: dst[(n>>4)][(k>>3)][n&15][k&7]
//   flat = (n>>4)*((K/8)*128) + (k>>3)*128 + (n&15)*8 + (k&7)
// Wq is pre-scaled by 0.25*log2(e) (softmax scale folded into Q).
#define WS_EMB 0                      // [96][128]   ctS=2048
#define WS_WQ  12288                  // 4x[128][128] ctS=2048
#define WS_WK  (WS_WQ + 65536)
#define WS_WV  (WS_WK + 65536)
#define WS_WO  (WS_WV + 65536)
#define WS_W1  (WS_WO + 65536)        // 4x[512][128] ctS=2048
#define WS_W2  (WS_W1 + 262144)       // 4x[128][512] ctS=8192
#define WS_END (WS_W2 + 262144)

__device__ __forceinline__ short f2bf(float f) {
  union { __hip_bfloat16 h; unsigned short s; } u;
  u.h = __float2bfloat16(f);
  return (short)u.s;
}
__device__ __forceinline__ bf16x4 pk4(f32x4 v) {
  bf16x4 r;
  r[0] = f2bf(v[0]); r[1] = f2bf(v[1]); r[2] = f2bf(v[2]); r[3] = f2bf(v[3]);
  return r;
}
__device__ __forceinline__ float gelu1(float x) {
  float y = x * __builtin_fmaf(0.0356774081f, x * x, 0.7978845608f);
  return x * __builtin_amdgcn_rcpf(1.f + exp2f(-2.885390082f * y));
}

__global__ void prep_weights(const float* __restrict__ tok_emb,
                             const float* __restrict__ Wq, const float* __restrict__ Wk,
                             const float* __restrict__ Wv, const float* __restrict__ Wo,
                             const float* __restrict__ W1, const float* __restrict__ W2,
                             short* __restrict__ wsb) {
  const float KSC = 0.360673760f;      // 0.25 * log2(e), folded into Wq
  int i = blockIdx.x * PREP_THR + threadIdx.x;
  if (i < 12288) {                       // tok_emb [96][128]
    int n = i >> 7, k = i & 127;
    wsb[WS_EMB + (n >> 4) * 2048 + (k >> 3) * 128 + (n & 15) * 8 + (k & 7)] =
        f2bf(tok_emb[i]);
    return;
  }
  i -= 12288;
  if (i < 262144) {                      // Wq,Wk,Wv,Wo: [4][128][128] each
    int tensor = i >> 16;
    int rem = i & 65535;
    int l = rem >> 14;
    int w = rem & 16383;
    int n = w >> 7, k = w & 127;
    const float* src = tensor == 0 ? Wq : tensor == 1 ? Wk : tensor == 2 ? Wv : Wo;
    float v = src[rem];
    if (tensor == 0) v *= KSC;
    wsb[WS_WQ + tensor * 65536 + l * 16384 +
        (n >> 4) * 2048 + (k >> 3) * 128 + (n & 15) * 8 + (k & 7)] = f2bf(v);
    return;
  }
  i -= 262144;
  if (i < 262144) {                      // W1 [4][512][128]
    int l = i >> 16;
    int w = i & 65535;
    int n = w >> 7, k = w & 127;
    wsb[WS_W1 + l * 65536 +
        (n >> 4) * 2048 + (k >> 3) * 128 + (n & 15) * 8 + (k & 7)] = f2bf(W1[i]);
    return;
  }
  i -= 262144;
  if (i < 262144) {                      // W2 [4][128][512]
    int l = i >> 16;
    int w = i & 65535;
    int n = w >> 9, k = w & 511;
    wsb[WS_W2 + l * 65536 +
        (n >> 4) * 8192 + (k >> 3) * 128 + (n & 15) * 8 + (k & 7)] = f2bf(W2[i]);
  }
}

// One block per sequence, 256 threads = 4 waves; 2 blocks/CU (the proven
// spill-free operating point). R16 + FF1 single-pass a1[4][4] (R10-proven at
// this config) + Wq pre-scale. Wave owns 32 dims (2 heads).
// x[cg][n][r] = X^T[wave*32+cg*16+lg*4+r][16n+lr].
__global__ __launch_bounds__(256, 2)
void lm_forward(const int* __restrict__ idx, const int* __restrict__ targets,
                const float* __restrict__ tok_emb, const float* __restrict__ pos_emb,
                const float* __restrict__ bo, const float* __restrict__ ln1_g,
                const float* __restrict__ ln1_b, const float* __restrict__ ln2_g,
                const float* __restrict__ ln2_b, const float* __restrict__ b1,
                const float* __restrict__ b2, const float* __restrict__ lnf_g,
                const float* __restrict__ lnf_b, const float* __restrict__ lm_b,
                const short* __restrict__ wsb, float* __restrict__ out,
                float* __restrict__ loss_part) {
  __shared__ __align__(16) short sXn[64 * 136];      // 17408 B (LN out)
  __shared__ __align__(16) char region[33792];       // sAtt[64][136] / sH[64][264] / sL[64][100]f32
  __shared__ __align__(16) float sPart[4 * 64 * 2];  // 2048 B LN partials
  __shared__ float sRed[64];
  short* sAtt = (short*)region;
  short* sH = (short*)region;
  float* sL = (float*)region;

  const int b = blockIdx.x;
  const int tid = threadIdx.x;
  const int wave = tid >> 6;       // 0..3
  const int lane = tid & 63;
  const int lr = lane & 15;
  const int lg = lane >> 4;
  const f32x4 fz = {0.f, 0.f, 0.f, 0.f};

  // ---- embedding: residual regs (wave owns dims wave*32 .. +31) ----
  f32x4 x[2][4];
#pragma unroll
  for (int cg = 0; cg < 2; ++cg)
#pragma unroll
    for (int n = 0; n < 4; ++n) {
      int t = 16 * n + lr;
      int dim = wave * 32 + cg * 16 + lg * 4;
      int tk = idx[b * 64 + t];
      x[cg][n] = *(const f32x4*)(tok_emb + tk * 128 + dim) +
                 *(const f32x4*)(pos_emb + t * 128 + dim);
    }

  // LN on reg residual; 2 barriers; writes sXn.
  auto ln = [&](const float* g, const float* be) {
    float s[4], s2[4];
#pragma unroll
    for (int n = 0; n < 4; ++n) {
      float a = 0.f, a2 = 0.f;
#pragma unroll
      for (int cg = 0; cg < 2; ++cg)
#pragma unroll
        for (int r = 0; r < 4; ++r) {
          float v = x[cg][n][r];
          a += v; a2 += v * v;
        }
      s[n] = a; s2[n] = a2;
    }
#pragma unroll
    for (int n = 0; n < 4; ++n) {
      s[n] += __shfl_xor(s[n], 16, 64);  s[n] += __shfl_xor(s[n], 32, 64);
      s2[n] += __shfl_xor(s2[n], 16, 64); s2[n] += __shfl_xor(s2[n], 32, 64);
    }
    if (lg == 0) {
#pragma unroll
      for (int n = 0; n < 4; ++n) {
        float2 p; p.x = s[n]; p.y = s2[n];
        *(float2*)(sPart + (wave * 64 + 16 * n + lr) * 2) = p;
      }
    }
    __syncthreads();
    f32x4 g4[2], b4[2];
#pragma unroll
    for (int cg = 0; cg < 2; ++cg) {
      int dim = wave * 32 + cg * 16 + lg * 4;
      g4[cg] = *(const f32x4*)(g + dim);
      b4[cg] = *(const f32x4*)(be + dim);
    }
#pragma unroll
    for (int n = 0; n < 4; ++n) {
      float S = 0.f, S2 = 0.f;
#pragma unroll
      for (int w = 0; w < 4; ++w) {
        float2 p = *(const float2*)(sPart + (w * 64 + 16 * n + lr) * 2);
        S += p.x; S2 += p.y;
      }
      float mean = S * 0.0078125f;
      float rstd = rsqrtf(__builtin_fmaf(-mean, mean, S2 * 0.0078125f) + 1e-5f);
#pragma unroll
      for (int cg = 0; cg < 2; ++cg) {
        f32x4 o;
#pragma unroll
        for (int c = 0; c < 4; ++c)
          o[c] = __builtin_fmaf((x[cg][n][c] - mean) * rstd, g4[cg][c], b4[cg][c]);
        *(bf16x4*)(sXn + (16 * n + lr) * 136 + wave * 32 + cg * 16 + lg * 4) = pk4(o);
      }
    }
    __syncthreads();
  };

#pragma unroll 1
  for (int l = 0; l < 4; ++l) {
    ln(ln1_g + l * 128, ln1_b + l * 128);

    // ---- QKV + attention, per head (wave owns heads 2*wave, 2*wave+1) ----
    const short* wq = wsb + WS_WQ + l * 16384;
    const short* wk = wsb + WS_WK + l * 16384;
    const short* wv = wsb + WS_WV + l * 16384;
#pragma unroll
    for (int hs = 0; hs < 2; ++hs) {
      const int h = wave * 2 + hs;
      f32x4 aq[4], ak[4], av[4];
#pragma unroll
      for (int n = 0; n < 4; ++n) { aq[n] = fz; ak[n] = fz; av[n] = fz; }
      const int wbase = h * 2048 + lg * 128 + lr * 8;
#pragma unroll
      for (int ks = 0; ks < 4; ++ks) {
        bf16x8 xf[4];
#pragma unroll
        for (int n = 0; n < 4; ++n)
          xf[n] = *(const bf16x8*)(sXn + (16 * n + lr) * 136 + ks * 32 + lg * 8);
        int wo_ = wbase + ks * 512;
        bf16x8 qw = *(const bf16x8*)(wq + wo_);
        bf16x8 kw = *(const bf16x8*)(wk + wo_);
        bf16x8 vw = *(const bf16x8*)(wv + wo_);
#pragma unroll
        for (int n = 0; n < 4; ++n) {
          aq[n] = MFMA32(qw, xf[n], aq[n]);
          ak[n] = MFMA32(kw, xf[n], ak[n]);
          av[n] = MFMA32(xf[n], vw, av[n]);
        }
      }
      bf16x4 qf[4], kf[4], vf[4];
#pragma unroll
      for (int n = 0; n < 4; ++n) {
        qf[n] = pk4(aq[n]);              // scale pre-folded into Wq
        kf[n] = pk4(ak[n]);
        vf[n] = pk4(av[n]);
      }
      // in-register attention: max-free exp2 softmax, deferred 1/Z, causal skip
      f32x4 sc[4][4];
#pragma unroll
      for (int n = 0; n < 4; ++n)
#pragma unroll
        for (int m = 0; m <= n; ++m)
          sc[m][n] = MFMA16(kf[m], qf[n], fz);
#pragma unroll
      for (int n = 0; n < 4; ++n) {
#pragma unroll
        for (int r = 0; r < 4; ++r)
          if (lg * 4 + r > lr) sc[n][n][r] = -1e30f;
        float sum = 0.f;
#pragma unroll
        for (int m = 0; m <= n; ++m)
#pragma unroll
          for (int r = 0; r < 4; ++r) {
            float p = exp2f(sc[m][n][r]);   // bounded: |sc| <= ~46
            sc[m][n][r] = p;
            sum += p;
          }
        f32x4 ao = fz;
#pragma unroll
        for (int m = 0; m <= n; ++m) {
          bf16x4 pf = pk4(sc[m][n]);
          ao = MFMA16(vf[m], pf, ao);
        }
        sum += __shfl_xor(sum, 16, 64);
        sum += __shfl_xor(sum, 32, 64);
        float rinv = __builtin_amdgcn_rcpf(sum);
        *(bf16x4*)(sAtt + (16 * n + lr) * 136 + h * 16 + lg * 4) = pk4(ao * rinv);
      }
    }
    __syncthreads();

    // ---- Wo: accumulate directly into residual regs (cols wave*32..+31) ----
    {
      const short* wo = wsb + WS_WO + l * 16384;
      const int wbase = wave * 4096 + lg * 128 + lr * 8;
#pragma unroll
      for (int ks = 0; ks < 4; ++ks) {
        bf16x8 af[4];
#pragma unroll
        for (int n = 0; n < 4; ++n)
          af[n] = *(const bf16x8*)(sAtt + (16 * n + lr) * 136 + ks * 32 + lg * 8);
#pragma unroll
        for (int cg = 0; cg < 2; ++cg) {
          bf16x8 wf = *(const bf16x8*)(wo + wbase + cg * 2048 + ks * 512);
#pragma unroll
          for (int n = 0; n < 4; ++n) x[cg][n] = MFMA32(wf, af[n], x[cg][n]);
        }
      }
#pragma unroll
      for (int cg = 0; cg < 2; ++cg) {
        f32x4 bo4 = *(const f32x4*)(bo + l * 128 + wave * 32 + cg * 16 + lg * 4);
#pragma unroll
        for (int n = 0; n < 4; ++n) x[cg][n] = x[cg][n] + bo4;
      }
    }

    ln(ln2_g + l * 128, ln2_b + l * 128);

    // ---- FF: 2 hidden chunks of 256; FF1 single-pass a1[4][4] (R10-proven);
    //      FF2 accumulates directly into residual regs ----
    {
      const short* w1 = wsb + WS_W1 + l * 65536;
      const short* w2 = wsb + WS_W2 + l * 65536;
#pragma unroll 1
      for (int c = 0; c < 2; ++c) {
        const int w1base = (c * 16 + wave * 4) * 2048 + lg * 128 + lr * 8;
        f32x4 a1[4][4];
#pragma unroll
        for (int g = 0; g < 4; ++g)
#pragma unroll
          for (int n = 0; n < 4; ++n) a1[g][n] = fz;
#pragma unroll
        for (int ks = 0; ks < 4; ++ks) {
          bf16x8 xf[4];
#pragma unroll
          for (int n = 0; n < 4; ++n)
            xf[n] = *(const bf16x8*)(sXn + (16 * n + lr) * 136 + ks * 32 + lg * 8);
#pragma unroll
          for (int g = 0; g < 4; ++g) {
            bf16x8 wf = *(const bf16x8*)(w1 + w1base + g * 2048 + ks * 512);
#pragma unroll
            for (int n = 0; n < 4; ++n) a1[g][n] = MFMA32(wf, xf[n], a1[g][n]);
          }
        }
#pragma unroll
        for (int g = 0; g < 4; ++g) {
          f32x4 b1v = *(const f32x4*)(b1 + l * 512 + c * 256 + wave * 64 +
                                      g * 16 + lg * 4);
#pragma unroll
          for (int n = 0; n < 4; ++n) {
            f32x4 hv;
#pragma unroll
            for (int r = 0; r < 4; ++r) hv[r] = gelu1(a1[g][n][r] + b1v[r]);
            *(bf16x4*)(sH + (16 * n + lr) * 264 + wave * 64 + g * 16 + lg * 4) = pk4(hv);
          }
        }
        __syncthreads();
#pragma unroll
        for (int ks = 0; ks < 8; ++ks) {
          bf16x8 hf[4];
#pragma unroll
          for (int n = 0; n < 4; ++n)
            hf[n] = *(const bf16x8*)(sH + (16 * n + lr) * 264 + ks * 32 + lg * 8);
#pragma unroll
          for (int cg = 0; cg < 2; ++cg) {
            bf16x8 wf = *(const bf16x8*)(w2 + (wave * 2 + cg) * 8192 + c * 4096 +
                                         ks * 512 + lg * 128 + lr * 8);
#pragma unroll
            for (int n = 0; n < 4; ++n) x[cg][n] = MFMA32(wf, hf[n], x[cg][n]);
          }
        }
        if (c == 0) __syncthreads();
      }
#pragma unroll
      for (int cg = 0; cg < 2; ++cg) {
        f32x4 b2v = *(const f32x4*)(b2 + l * 128 + wave * 32 + cg * 16 + lg * 4);
#pragma unroll
        for (int n = 0; n < 4; ++n) x[cg][n] = x[cg][n] + b2v;
      }
    }
  }

  // ---- final LN ----
  ln(lnf_g, lnf_b);

  // ---- logits: vocab tiles {wave} + {wave+4 if wave<2} ----
  {
    auto do_tile = [&](int vt) {
      f32x4 al[4];
#pragma unroll
      for (int n = 0; n < 4; ++n) al[n] = fz;
#pragma unroll
      for (int ks = 0; ks < 4; ++ks) {
        bf16x8 ef = *(const bf16x8*)(wsb + WS_EMB + vt * 2048 + ks * 512 +
                                     lg * 128 + lr * 8);
#pragma unroll
        for (int n = 0; n < 4; ++n) {
          bf16x8 xf = *(const bf16x8*)(sXn + (16 * n + lr) * 136 + ks * 32 + lg * 8);
          al[n] = MFMA32(ef, xf, al[n]);
        }
      }
      f32x4 lb = *(const f32x4*)(lm_b + vt * 16 + lg * 4);
#pragma unroll
      for (int n = 0; n < 4; ++n) {
        f32x4 v = al[n] + lb;
        int t = 16 * n + lr;
        *(f32x4*)(out + ((size_t)b * 64 + t) * 96 + vt * 16 + lg * 4) = v;
        *(f32x4*)(sL + t * 100 + vt * 16 + lg * 4) = v;
      }
    };
    do_tile(wave);
    if (wave < 2) do_tile(wave + 4);
  }
  __syncthreads();

  // ---- per-row cross-entropy (4 threads/row, 24 cols each; max-free, logits small) ----
  {
    int r = tid >> 2, c4 = tid & 3;
    const float* lrow = sL + r * 100 + c4 * 24;
    float sum = 0.f;
#pragma unroll
    for (int j = 0; j < 24; ++j) sum += __expf(lrow[j]);
    sum += __shfl_xor(sum, 1, 64);
    sum += __shfl_xor(sum, 2, 64);
    if (c4 == 0) {
      float lse = logf(sum);
      sRed[r] = lse - sL[r * 100 + targets[b * 64 + r]];
    }
  }
  __syncthreads();
  if (wave == 0) {
    float v = sRed[lane];
#pragma unroll
    for (int m = 32; m >= 1; m >>= 1) v += __shfl_xor(v, m, 64);
    if (lane == 0) loss_part[b] = v;
  }
}

__global__ void loss_reduce(const float* __restrict__ loss_part, float* __restrict__ out_loss) {
  __shared__ float red[256];
  int t = threadIdx.x;
  float s = 0.f;
  for (int i = t; i < 4096; i += 256) s += loss_part[i];
  red[t] = s;
  __syncthreads();
  for (int k = 128; k >= 1; k >>= 1) {
    if (t < k) red[t] += red[t + k];
    __syncthreads();
  }
  if (t == 0) out_loss[0] = red[0] * (1.f / 262144.f);
}

extern "C" void kernel_launch(void* const* d_in, const int* in_sizes, int n_in,
                              void* d_out, int out_size, void* d_ws, size_t ws_size,
                              hipStream_t stream) {
  (void)in_sizes; (void)n_in; (void)ws_size;
  const int* idx      = (const int*)d_in[0];
  const int* targets  = (const int*)d_in[1];
  const float* tok_emb = (const float*)d_in[2];
  const float* pos_emb = (const float*)d_in[3];
  const float* Wq = (const float*)d_in[4];
  const float* Wk = (const float*)d_in[5];
  const float* Wv = (const float*)d_in[6];
  const float* Wo = (const float*)d_in[7];
  const float* bo = (const float*)d_in[8];
  const float* ln1_g = (const float*)d_in[9];
  const float* ln1_b = (const float*)d_in[10];
  const float* ln2_g = (const float*)d_in[11];
  const float* ln2_b = (const float*)d_in[12];
  const float* W1 = (const float*)d_in[13];
  const float* b1 = (const float*)d_in[14];
  const float* W2 = (const float*)d_in[15];
  const float* b2 = (const float*)d_in[16];
  const float* lnf_g = (const float*)d_in[17];
  const float* lnf_b = (const float*)d_in[18];
  const float* lm_b = (const float*)d_in[19];

  short* wsb = (short*)d_ws;
  float* loss_part = (float*)((char*)d_ws + (size_t)WS_END * 2);
  float* out = (float*)d_out;

  prep_weights<<<1560, PREP_THR, 0, stream>>>(tok_emb, Wq, Wk, Wv, Wo, W1, W2, wsb);
  lm_forward<<<4096, 256, 0, stream>>>(idx, targets, tok_emb, pos_emb, bo,
                                       ln1_g, ln1_b, ln2_g, ln2_b, b1, b2,
                                       lnf_g, lnf_b, lm_b, wsb, out, loss_part);
  loss_reduce<<<1, 256, 0, stream>>>(loss_part, out + (out_size - 1));
}

// Round 18
// 796.988 us; speedup vs baseline: 1.0527x; 1.0527x over previous
//
#include <hip/hip_runtime.h>
#include <hip/hip_bf16.h>
#include <math.h>

// Problem constants: V=96, D=128, T=64, H=8, HD=16, FF=512, L=4, B=4096
#define PREP_THR 512

typedef __attribute__((ext_vector_type(8))) short bf16x8;
typedef __attribute__((ext_vector_type(4))) short bf16x4;
typedef __attribute__((ext_vector_type(4))) float f32x4;

#define MFMA32(a, b, c) __builtin_amdgcn_mfma_f32_16x16x32_bf16((a), (b), (c), 0, 0, 0)

#if defined(__has_builtin)
#if __has_builtin(__builtin_amdgcn_mfma_f32_16x16x16bf16_1k)
#define HAVE_MFMA16 1
#endif
#endif
#ifdef HAVE_MFMA16
#define MFMA16(a, b, c) __builtin_amdgcn_mfma_f32_16x16x16bf16_1k((a), (b), (c), 0, 0, 0)
#else
__device__ __forceinline__ f32x4 mfma16_fb(bf16x4 a, bf16x4 b, f32x4 c) {
  asm volatile("s_nop 1\n\tv_mfma_f32_16x16x16_bf16 %0, %1, %2, %0\n\ts_nop 7\n\ts_nop 7"
               : "+v"(c) : "v"(a), "v"(b));
  return c;
}
#define MFMA16(a, b, c) mfma16_fb((a), (b), (c))
#endif

// ---- workspace layout (bf16 element offsets) ----
// Weights bf16, TILE-MAJOR swizzle: dst[(n>>4)][(k>>3)][n&15][k&7]
//   flat = (n>>4)*((K/8)*128) + (k>>3)*128 + (n&15)*8 + (k&7)
// Wq pre-scaled by 0.25*log2(e) (softmax scale folded in).
#define WS_EMB 0                      // [96][128]   ctS=2048
#define WS_WQ  12288                  // 4x[128][128] ctS=2048
#define WS_WK  (WS_WQ + 65536)
#define WS_WV  (WS_WK + 65536)
#define WS_WO  (WS_WV + 65536)
#define WS_W1  (WS_WO + 65536)        // 4x[512][128] ctS=2048
#define WS_W2  (WS_W1 + 262144)       // 4x[128][512] ctS=8192
#define WS_END (WS_W2 + 262144)

__device__ __forceinline__ short f2bf(float f) {
  union { __hip_bfloat16 h; unsigned short s; } u;
  u.h = __float2bfloat16(f);
  return (short)u.s;
}
__device__ __forceinline__ bf16x4 pk4(f32x4 v) {
  bf16x4 r;
  r[0] = f2bf(v[0]); r[1] = f2bf(v[1]); r[2] = f2bf(v[2]); r[3] = f2bf(v[3]);
  return r;
}
__device__ __forceinline__ float gelu1(float x) {
  float y = x * __builtin_fmaf(0.0356774081f, x * x, 0.7978845608f);
  return x * __builtin_amdgcn_rcpf(1.f + exp2f(-2.885390082f * y));
}

__global__ void prep_weights(const float* __restrict__ tok_emb,
                             const float* __restrict__ Wq, const float* __restrict__ Wk,
                             const float* __restrict__ Wv, const float* __restrict__ Wo,
                             const float* __restrict__ W1, const float* __restrict__ W2,
                             short* __restrict__ wsb) {
  const float KSC = 0.360673760f;      // 0.25 * log2(e), folded into Wq
  int i = blockIdx.x * PREP_THR + threadIdx.x;
  if (i < 12288) {                       // tok_emb [96][128]
    int n = i >> 7, k = i & 127;
    wsb[WS_EMB + (n >> 4) * 2048 + (k >> 3) * 128 + (n & 15) * 8 + (k & 7)] =
        f2bf(tok_emb[i]);
    return;
  }
  i -= 12288;
  if (i < 262144) {                      // Wq,Wk,Wv,Wo: [4][128][128] each
    int tensor = i >> 16;
    int rem = i & 65535;
    int l = rem >> 14;
    int w = rem & 16383;
    int n = w >> 7, k = w & 127;
    const float* src = tensor == 0 ? Wq : tensor == 1 ? Wk : tensor == 2 ? Wv : Wo;
    float v = src[rem];
    if (tensor == 0) v *= KSC;
    wsb[WS_WQ + tensor * 65536 + l * 16384 +
        (n >> 4) * 2048 + (k >> 3) * 128 + (n & 15) * 8 + (k & 7)] = f2bf(v);
    return;
  }
  i -= 262144;
  if (i < 262144) {                      // W1 [4][512][128]
    int l = i >> 16;
    int w = i & 65535;
    int n = w >> 7, k = w & 127;
    wsb[WS_W1 + l * 65536 +
        (n >> 4) * 2048 + (k >> 3) * 128 + (n & 15) * 8 + (k & 7)] = f2bf(W1[i]);
    return;
  }
  i -= 262144;
  if (i < 262144) {                      // W2 [4][128][512]
    int l = i >> 16;
    int w = i & 65535;
    int n = w >> 9, k = w & 511;
    wsb[WS_W2 + l * 65536 +
        (n >> 4) * 8192 + (k >> 3) * 128 + (n & 15) * 8 + (k & 7)] = f2bf(W2[i]);
  }
}

// One block per sequence, 256 threads = 4 waves; 2 blocks/CU (proven spill-free
// operating point). R16 structure EXACTLY (785us best) + Wq pre-scale only.
// R17 lesson: at 2 waves/SIMD, FF1's smaller acc set (2 g-passes, 32 acc) beats
// the merged 64-acc version despite extra LDS reads — scheduler freedom wins.
// Wave owns 32 dims (2 heads). x[cg][n][r] = X^T[wave*32+cg*16+lg*4+r][16n+lr].
__global__ __launch_bounds__(256, 2)
void lm_forward(const int* __restrict__ idx, const int* __restrict__ targets,
                const float* __restrict__ tok_emb, const float* __restrict__ pos_emb,
                const float* __restrict__ bo, const float* __restrict__ ln1_g,
                const float* __restrict__ ln1_b, const float* __restrict__ ln2_g,
                const float* __restrict__ ln2_b, const float* __restrict__ b1,
                const float* __restrict__ b2, const float* __restrict__ lnf_g,
                const float* __restrict__ lnf_b, const float* __restrict__ lm_b,
                const short* __restrict__ wsb, float* __restrict__ out,
                float* __restrict__ loss_part) {
  __shared__ __align__(16) short sXn[64 * 136];      // 17408 B (LN out)
  __shared__ __align__(16) char region[33792];       // sAtt[64][136] / sH[64][264] / sL[64][100]f32
  __shared__ __align__(16) float sPart[4 * 64 * 2];  // 2048 B LN partials
  __shared__ float sRed[64];
  short* sAtt = (short*)region;
  short* sH = (short*)region;
  float* sL = (float*)region;

  const int b = blockIdx.x;
  const int tid = threadIdx.x;
  const int wave = tid >> 6;       // 0..3
  const int lane = tid & 63;
  const int lr = lane & 15;
  const int lg = lane >> 4;
  const f32x4 fz = {0.f, 0.f, 0.f, 0.f};

  // ---- embedding: residual regs (wave owns dims wave*32 .. +31) ----
  f32x4 x[2][4];
#pragma unroll
  for (int cg = 0; cg < 2; ++cg)
#pragma unroll
    for (int n = 0; n < 4; ++n) {
      int t = 16 * n + lr;
      int dim = wave * 32 + cg * 16 + lg * 4;
      int tk = idx[b * 64 + t];
      x[cg][n] = *(const f32x4*)(tok_emb + tk * 128 + dim) +
                 *(const f32x4*)(pos_emb + t * 128 + dim);
    }

  // LN on reg residual; 2 barriers; writes sXn.
  auto ln = [&](const float* g, const float* be) {
    float s[4], s2[4];
#pragma unroll
    for (int n = 0; n < 4; ++n) {
      float a = 0.f, a2 = 0.f;
#pragma unroll
      for (int cg = 0; cg < 2; ++cg)
#pragma unroll
        for (int r = 0; r < 4; ++r) {
          float v = x[cg][n][r];
          a += v; a2 += v * v;
        }
      s[n] = a; s2[n] = a2;
    }
#pragma unroll
    for (int n = 0; n < 4; ++n) {
      s[n] += __shfl_xor(s[n], 16, 64);  s[n] += __shfl_xor(s[n], 32, 64);
      s2[n] += __shfl_xor(s2[n], 16, 64); s2[n] += __shfl_xor(s2[n], 32, 64);
    }
    if (lg == 0) {
#pragma unroll
      for (int n = 0; n < 4; ++n) {
        float2 p; p.x = s[n]; p.y = s2[n];
        *(float2*)(sPart + (wave * 64 + 16 * n + lr) * 2) = p;
      }
    }
    __syncthreads();
    f32x4 g4[2], b4[2];
#pragma unroll
    for (int cg = 0; cg < 2; ++cg) {
      int dim = wave * 32 + cg * 16 + lg * 4;
      g4[cg] = *(const f32x4*)(g + dim);
      b4[cg] = *(const f32x4*)(be + dim);
    }
#pragma unroll
    for (int n = 0; n < 4; ++n) {
      float S = 0.f, S2 = 0.f;
#pragma unroll
      for (int w = 0; w < 4; ++w) {
        float2 p = *(const float2*)(sPart + (w * 64 + 16 * n + lr) * 2);
        S += p.x; S2 += p.y;
      }
      float mean = S * 0.0078125f;
      float rstd = rsqrtf(__builtin_fmaf(-mean, mean, S2 * 0.0078125f) + 1e-5f);
#pragma unroll
      for (int cg = 0; cg < 2; ++cg) {
        f32x4 o;
#pragma unroll
        for (int c = 0; c < 4; ++c)
          o[c] = __builtin_fmaf((x[cg][n][c] - mean) * rstd, g4[cg][c], b4[cg][c]);
        *(bf16x4*)(sXn + (16 * n + lr) * 136 + wave * 32 + cg * 16 + lg * 4) = pk4(o);
      }
    }
    __syncthreads();
  };

#pragma unroll 1
  for (int l = 0; l < 4; ++l) {
    ln(ln1_g + l * 128, ln1_b + l * 128);

    // ---- QKV + attention, per head (wave owns heads 2*wave, 2*wave+1) ----
    const short* wq = wsb + WS_WQ + l * 16384;
    const short* wk = wsb + WS_WK + l * 16384;
    const short* wv = wsb + WS_WV + l * 16384;
#pragma unroll
    for (int hs = 0; hs < 2; ++hs) {
      const int h = wave * 2 + hs;
      f32x4 aq[4], ak[4], av[4];
#pragma unroll
      for (int n = 0; n < 4; ++n) { aq[n] = fz; ak[n] = fz; av[n] = fz; }
      const int wbase = h * 2048 + lg * 128 + lr * 8;
#pragma unroll
      for (int ks = 0; ks < 4; ++ks) {
        bf16x8 xf[4];
#pragma unroll
        for (int n = 0; n < 4; ++n)
          xf[n] = *(const bf16x8*)(sXn + (16 * n + lr) * 136 + ks * 32 + lg * 8);
        int wo_ = wbase + ks * 512;
        bf16x8 qw = *(const bf16x8*)(wq + wo_);
        bf16x8 kw = *(const bf16x8*)(wk + wo_);
        bf16x8 vw = *(const bf16x8*)(wv + wo_);
#pragma unroll
        for (int n = 0; n < 4; ++n) {
          aq[n] = MFMA32(qw, xf[n], aq[n]);
          ak[n] = MFMA32(kw, xf[n], ak[n]);
          av[n] = MFMA32(xf[n], vw, av[n]);
        }
      }
      bf16x4 qf[4], kf[4], vf[4];
#pragma unroll
      for (int n = 0; n < 4; ++n) {
        qf[n] = pk4(aq[n]);              // scale pre-folded into Wq
        kf[n] = pk4(ak[n]);
        vf[n] = pk4(av[n]);
      }
      // in-register attention: max-free exp2 softmax, deferred 1/Z, causal skip
      f32x4 sc[4][4];
#pragma unroll
      for (int n = 0; n < 4; ++n)
#pragma unroll
        for (int m = 0; m <= n; ++m)
          sc[m][n] = MFMA16(kf[m], qf[n], fz);
#pragma unroll
      for (int n = 0; n < 4; ++n) {
#pragma unroll
        for (int r = 0; r < 4; ++r)
          if (lg * 4 + r > lr) sc[n][n][r] = -1e30f;
        float sum = 0.f;
#pragma unroll
        for (int m = 0; m <= n; ++m)
#pragma unroll
          for (int r = 0; r < 4; ++r) {
            float p = exp2f(sc[m][n][r]);   // bounded: |sc| <= ~46
            sc[m][n][r] = p;
            sum += p;
          }
        f32x4 ao = fz;
#pragma unroll
        for (int m = 0; m <= n; ++m) {
          bf16x4 pf = pk4(sc[m][n]);
          ao = MFMA16(vf[m], pf, ao);
        }
        sum += __shfl_xor(sum, 16, 64);
        sum += __shfl_xor(sum, 32, 64);
        float rinv = __builtin_amdgcn_rcpf(sum);
        *(bf16x4*)(sAtt + (16 * n + lr) * 136 + h * 16 + lg * 4) = pk4(ao * rinv);
      }
    }
    __syncthreads();

    // ---- Wo: accumulate directly into residual regs (cols wave*32..+31) ----
    {
      const short* wo = wsb + WS_WO + l * 16384;
      const int wbase = wave * 4096 + lg * 128 + lr * 8;
#pragma unroll
      for (int ks = 0; ks < 4; ++ks) {
        bf16x8 af[4];
#pragma unroll
        for (int n = 0; n < 4; ++n)
          af[n] = *(const bf16x8*)(sAtt + (16 * n + lr) * 136 + ks * 32 + lg * 8);
#pragma unroll
        for (int cg = 0; cg < 2; ++cg) {
          bf16x8 wf = *(const bf16x8*)(wo + wbase + cg * 2048 + ks * 512);
#pragma unroll
          for (int n = 0; n < 4; ++n) x[cg][n] = MFMA32(wf, af[n], x[cg][n]);
        }
      }
#pragma unroll
      for (int cg = 0; cg < 2; ++cg) {
        f32x4 bo4 = *(const f32x4*)(bo + l * 128 + wave * 32 + cg * 16 + lg * 4);
#pragma unroll
        for (int n = 0; n < 4; ++n) x[cg][n] = x[cg][n] + bo4;
      }
    }

    ln(ln2_g + l * 128, ln2_b + l * 128);

    // ---- FF: 2 hidden chunks of 256; FF1 in 2 g-passes (acc 32);
    //      FF2 accumulates directly into residual regs ----
    {
      const short* w1 = wsb + WS_W1 + l * 65536;
      const short* w2 = wsb + WS_W2 + l * 65536;
#pragma unroll 1
      for (int c = 0; c < 2; ++c) {
        const int w1base = (c * 16 + wave * 4) * 2048 + lg * 128 + lr * 8;
#pragma unroll 1
        for (int g2 = 0; g2 < 2; ++g2) {
          f32x4 a1[2][4];
#pragma unroll
          for (int gg = 0; gg < 2; ++gg)
#pragma unroll
            for (int n = 0; n < 4; ++n) a1[gg][n] = fz;
#pragma unroll
          for (int ks = 0; ks < 4; ++ks) {
            bf16x8 xf[4];
#pragma unroll
            for (int n = 0; n < 4; ++n)
              xf[n] = *(const bf16x8*)(sXn + (16 * n + lr) * 136 + ks * 32 + lg * 8);
#pragma unroll
            for (int gg = 0; gg < 2; ++gg) {
              bf16x8 wf = *(const bf16x8*)(w1 + w1base + (g2 * 2 + gg) * 2048 + ks * 512);
#pragma unroll
              for (int n = 0; n < 4; ++n) a1[gg][n] = MFMA32(wf, xf[n], a1[gg][n]);
            }
          }
#pragma unroll
          for (int gg = 0; gg < 2; ++gg) {
            f32x4 b1v = *(const f32x4*)(b1 + l * 512 + c * 256 + wave * 64 +
                                        (g2 * 2 + gg) * 16 + lg * 4);
#pragma unroll
            for (int n = 0; n < 4; ++n) {
              f32x4 hv;
#pragma unroll
              for (int r = 0; r < 4; ++r) hv[r] = gelu1(a1[gg][n][r] + b1v[r]);
              *(bf16x4*)(sH + (16 * n + lr) * 264 + wave * 64 +
                         (g2 * 2 + gg) * 16 + lg * 4) = pk4(hv);
            }
          }
        }
        __syncthreads();
#pragma unroll
        for (int ks = 0; ks < 8; ++ks) {
          bf16x8 hf[4];
#pragma unroll
          for (int n = 0; n < 4; ++n)
            hf[n] = *(const bf16x8*)(sH + (16 * n + lr) * 264 + ks * 32 + lg * 8);
#pragma unroll
          for (int cg = 0; cg < 2; ++cg) {
            bf16x8 wf = *(const bf16x8*)(w2 + (wave * 2 + cg) * 8192 + c * 4096 +
                                         ks * 512 + lg * 128 + lr * 8);
#pragma unroll
            for (int n = 0; n < 4; ++n) x[cg][n] = MFMA32(wf, hf[n], x[cg][n]);
          }
        }
        if (c == 0) __syncthreads();
      }
#pragma unroll
      for (int cg = 0; cg < 2; ++cg) {
        f32x4 b2v = *(const f32x4*)(b2 + l * 128 + wave * 32 + cg * 16 + lg * 4);
#pragma unroll
        for (int n = 0; n < 4; ++n) x[cg][n] = x[cg][n] + b2v;
      }
    }
  }

  // ---- final LN ----
  ln(lnf_g, lnf_b);

  // ---- logits: vocab tiles {wave} + {wave+4 if wave<2} ----
  {
    auto do_tile = [&](int vt) {
      f32x4 al[4];
#pragma unroll
      for (int n = 0; n < 4; ++n) al[n] = fz;
#pragma unroll
      for (int ks = 0; ks < 4; ++ks) {
        bf16x8 ef = *(const bf16x8*)(wsb + WS_EMB + vt * 2048 + ks * 512 +
                                     lg * 128 + lr * 8);
#pragma unroll
        for (int n = 0; n < 4; ++n) {
          bf16x8 xf = *(const bf16x8*)(sXn + (16 * n + lr) * 136 + ks * 32 + lg * 8);
          al[n] = MFMA32(ef, xf, al[n]);
        }
      }
      f32x4 lb = *(const f32x4*)(lm_b + vt * 16 + lg * 4);
#pragma unroll
      for (int n = 0; n < 4; ++n) {
        f32x4 v = al[n] + lb;
        int t = 16 * n + lr;
        *(f32x4*)(out + ((size_t)b * 64 + t) * 96 + vt * 16 + lg * 4) = v;
        *(f32x4*)(sL + t * 100 + vt * 16 + lg * 4) = v;
      }
    };
    do_tile(wave);
    if (wave < 2) do_tile(wave + 4);
  }
  __syncthreads();

  // ---- per-row cross-entropy (4 threads/row, 24 cols each; max-free, logits small) ----
  {
    int r = tid >> 2, c4 = tid & 3;
    const float* lrow = sL + r * 100 + c4 * 24;
    float sum = 0.f;
#pragma unroll
    for (int j = 0; j < 24; ++j) sum += __expf(lrow[j]);
    sum += __shfl_xor(sum, 1, 64);
    sum += __shfl_xor(sum, 2, 64);
    if (c4 == 0) {
      float lse = logf(sum);
      sRed[r] = lse - sL[r * 100 + targets[b * 64 + r]];
    }
  }
  __syncthreads();
  if (wave == 0) {
    float v = sRed[lane];
#pragma unroll
    for (int m = 32; m >= 1; m >>= 1) v += __shfl_xor(v, m, 64);
    if (lane == 0) loss_part[b] = v;
  }
}

__global__ void loss_reduce(const float* __restrict__ loss_part, float* __restrict__ out_loss) {
  __shared__ float red[256];
  int t = threadIdx.x;
  float s = 0.f;
  for (int i = t; i < 4096; i += 256) s += loss_part[i];
  red[t] = s;
  __syncthreads();
  for (int k = 128; k >= 1; k >>= 1) {
    if (t < k) red[t] += red[t + k];
    __syncthreads();
  }
  if (t == 0) out_loss[0] = red[0] * (1.f / 262144.f);
}

extern "C" void kernel_launch(void* const* d_in, const int* in_sizes, int n_in,
                              void* d_out, int out_size, void* d_ws, size_t ws_size,
                              hipStream_t stream) {
  (void)in_sizes; (void)n_in; (void)ws_size;
  const int* idx      = (const int*)d_in[0];
  const int* targets  = (const int*)d_in[1];
  const float* tok_emb = (const float*)d_in[2];
  const float* pos_emb = (const float*)d_in[3];
  const float* Wq = (const float*)d_in[4];
  const float* Wk = (const float*)d_in[5];
  const float* Wv = (const float*)d_in[6];
  const float* Wo = (const float*)d_in[7];
  const float* bo = (const float*)d_in[8];
  const float* ln1_g = (const float*)d_in[9];
  const float* ln1_b = (const float*)d_in[10];
  const float* ln2_g = (const float*)d_in[11];
  const float* ln2_b = (const float*)d_in[12];
  const float* W1 = (const float*)d_in[13];
  const float* b1 = (const float*)d_in[14];
  const float* W2 = (const float*)d_in[15];
  const float* b2 = (const float*)d_in[16];
  const float* lnf_g = (const float*)d_in[17];
  const float* lnf_b = (const float*)d_in[18];
  const float* lm_b = (const float*)d_in[19];

  short* wsb = (short*)d_ws;
  float* loss_part = (float*)((char*)d_ws + (size_t)WS_END * 2);
  float* out = (float*)d_out;

  prep_weights<<<1560, PREP_THR, 0, stream>>>(tok_emb, Wq, Wk, Wv, Wo, W1, W2, wsb);
  lm_forward<<<4096, 256, 0, stream>>>(idx, targets, tok_emb, pos_emb, bo,
                                       ln1_g, ln1_b, ln2_g, ln2_b, b1, b2,
                                       lnf_g, lnf_b, lm_b, wsb, out, loss_part);
  loss_reduce<<<1, 256, 0, stream>>>(loss_part, out + (out_size - 1));
}